// Round 10
// baseline (196.975 us; speedup 1.0000x reference)
//
#include <hip/hip_runtime.h>
#include <stdint.h>

// MultiHeadAttention w/ RoPE, causal. B=2, T=2048, C=1024, H=16, Dh=64.
// Round 22: GEMM overhaul (attn untouched, R21 version kept).
//  gemm_qkv counters: 581 TF, MfmaUtil 21, 3.3M bank conflicts, FETCH 35.9MB
//  vs 17MB compulsory -> 2-barrier latency structure + bank aliasing + A-panel
//  spread over 8 XCDs. Fixes:
//  (a) BK=64: 32 MFMA per barrier pair (was 16), barriers halved.
//  (b) T2 XOR swizzle via pre-swizzled GLDS16 SOURCE col (m173, rule #21):
//      LDS linear [128][64], src col-block sc^(sr&7), frag read col
//      (ks*4+quad)^(l16&7) -> conflict-free ds_read_b128.
//  (c) XCD-aware decode: xcd=L&7 owns (z,m) panels x all 8 n-tiles -> each
//      A-panel fetched into exactly one XCD L2.
//  Same treatment for gemm_out.

typedef float  f32x4  __attribute__((ext_vector_type(4)));
typedef float  f32x16 __attribute__((ext_vector_type(16)));
typedef __bf16 bf16x8 __attribute__((ext_vector_type(8)));
typedef unsigned int u32x2 __attribute__((ext_vector_type(2)));

#define GLDS16(gp, lp)                                                         \
  __builtin_amdgcn_global_load_lds(                                            \
      (const __attribute__((address_space(1))) void*)(gp),                     \
      (__attribute__((address_space(3))) void*)(lp), 16, 0, 0)

static __device__ __forceinline__ f32x4 zero4() {
  f32x4 z = {0.f, 0.f, 0.f, 0.f};
  return z;
}

static __device__ __forceinline__ bf16x8 cvt8(const float* __restrict__ p) {
  f32x4 u = *(const f32x4*)p;
  f32x4 v = *(const f32x4*)(p + 4);
  bf16x8 o;
#pragma unroll
  for (int j = 0; j < 4; ++j) o[j] = (__bf16)u[j];
#pragma unroll
  for (int j = 0; j < 4; ++j) o[4 + j] = (__bf16)v[j];
  return o;
}

// ---------------------------------------------------------------------------
// Prepass: x (4M f32) -> xb bf16; Wq/Wk/Wv/Wo (1M f32 each) -> Wb bf16[4][1M].
// ---------------------------------------------------------------------------
__global__ __launch_bounds__(256) void prep(
    const float* __restrict__ x,
    const float* __restrict__ Wq, const float* __restrict__ Wk,
    const float* __restrict__ Wv, const float* __restrict__ Wo,
    __bf16* __restrict__ xb, __bf16* __restrict__ Wb)
{
  size_t g = ((size_t)blockIdx.x * 256 + threadIdx.x) * 8;
  if (g < (size_t)4194304) {
    *(bf16x8*)&xb[g] = cvt8(x + g);
  } else {
    size_t j = g - 4194304;
    int w = (int)(j >> 20);
    size_t off = j & 1048575;
    const float* src = (w == 0) ? Wq : (w == 1) ? Wk : (w == 2) ? Wv : Wo;
    *(bf16x8*)&Wb[(size_t)w * 1048576 + off] = cvt8(src + off);
  }
}

// ---------------------------------------------------------------------------
// QKV GEMM: C[m][n] = sum_k xb[m][k]*W[n][k]. 128x128 tile, BK=64, GLDS16
// with pre-swizzled source col; conflict-free frag reads; XCD-aware decode.
// z<2: RoPE fused (Q pre-scaled by 0.125*log2e). z=2: V^T [bh][d][t].
// ---------------------------------------------------------------------------
__global__ __launch_bounds__(256) void gemm_qkv(
    const __bf16* __restrict__ xb, const __bf16* __restrict__ Wb,
    __bf16* __restrict__ Qp, __bf16* __restrict__ Kp, __bf16* __restrict__ Vt)
{
  __shared__ __bf16 As[128 * 64];
  __shared__ __bf16 Bs[128 * 64];
  __shared__ __bf16 Es[4 * 16 * 72];   // per-wave 16x72 transpose tile

  const int tid  = threadIdx.x;
  const int lane = tid & 63;
  const int wid  = tid >> 6;
  const int quad = lane >> 4;
  const int l16  = lane & 15;
  const int wm   = (wid >> 1) * 64;
  const int wn   = (wid & 1) * 64;

  // XCD decode: xcd=L&7 owns 12 (z,m) panels x all 8 n-tiles.
  const int L  = blockIdx.x;            // 768 blocks
  const int t  = L >> 3;                // 0..95
  const int n0 = (t & 7) * 128;
  const int zm = (L & 7) * 12 + (t >> 3);  // 0..95
  const int z  = zm % 3;
  const int m0 = (zm / 3) * 128;
  const __bf16* Bt = Wb + (size_t)z * 1048576;

  const int sr  = tid >> 3;             // 0..31 staging row within chunk
  const int scx = ((tid & 7) ^ (sr & 7)) * 8;  // pre-swizzled source col
  const int fx  = l16 & 7;              // frag-read xor term

  f32x4 acc[4][4];
  for (int i = 0; i < 4; ++i)
    for (int j = 0; j < 4; ++j) acc[i][j] = zero4();

  for (int k0 = 0; k0 < 1024; k0 += 64) {
    __syncthreads();
#pragma unroll
    for (int c = 0; c < 4; ++c) {
      GLDS16(xb + (size_t)(m0 + c * 32 + sr) * 1024 + k0 + scx,
             &As[c * 2048 + (size_t)tid * 8]);
      GLDS16(Bt + (size_t)(n0 + c * 32 + sr) * 1024 + k0 + scx,
             &Bs[c * 2048 + (size_t)tid * 8]);
    }
    __syncthreads();

#pragma unroll
    for (int ks = 0; ks < 2; ++ks) {
      bf16x8 af[4], bfr[4];
#pragma unroll
      for (int i = 0; i < 4; ++i)
        af[i] = *(const bf16x8*)
            &As[(wm + i * 16 + l16) * 64 + ((ks * 4 + quad) ^ fx) * 8];
#pragma unroll
      for (int i = 0; i < 4; ++i)
        bfr[i] = *(const bf16x8*)
            &Bs[(wn + i * 16 + l16) * 64 + ((ks * 4 + quad) ^ fx) * 8];
#pragma unroll
      for (int mt = 0; mt < 4; ++mt)
#pragma unroll
        for (int nt = 0; nt < 4; ++nt)
          acc[mt][nt] = __builtin_amdgcn_mfma_f32_16x16x32_bf16(
              af[mt], bfr[nt], acc[mt][nt], 0, 0, 0);
    }
  }

  // D layout: row = 4*quad + reg, col = l16 per 16x16 subtile.
  const int h = (n0 + wn) >> 6;
  __bf16* es = &Es[wid * 1152];        // 16 x 72, per-wave private
  const int rl = lane >> 3, ch = lane & 7;

  if (z < 2) {
    // fused RoPE; for Q (z==0) fold softmax scale 0.125*log2(e) into cv/sv.
    const float c0f = -13.287712379549449f / 32.0f;  // -log2(10000)/32
    const float f0 = exp2f((float)l16 * c0f);
    const float f1 = exp2f((float)(16 + l16) * c0f);
    const float SC = (z == 0) ? 0.125f * 1.44269504088896340736f : 1.0f;
    for (int mt = 0; mt < 4; ++mt)
      for (int r = 0; r < 4; ++r) {
        int gm = m0 + wm + mt * 16 + 4 * quad + r;
        float tt = (float)(gm & 2047);
        for (int nt = 0; nt < 2; ++nt) {
          float ang = tt * (nt ? f1 : f0);
          float cv = __cosf(ang) * SC, sv = __sinf(ang) * SC;
          float lo = acc[mt][nt][r], hi = acc[mt][nt + 2][r];
          acc[mt][nt][r]     = lo * cv - hi * sv;
          acc[mt][nt + 2][r] = hi * cv + lo * sv;
        }
      }
    __bf16* dst = (z == 0) ? Qp : Kp;
    for (int mt = 0; mt < 4; ++mt) {
      for (int nt = 0; nt < 4; ++nt)
        for (int r = 0; r < 4; ++r)
          es[(4 * quad + r) * 72 + nt * 16 + l16] = (__bf16)acc[mt][nt][r];
      size_t g0 = (size_t)(m0 + wm + mt * 16 + rl) * 1024 + n0 + wn + ch * 8;
      *(bf16x8*)&dst[g0]            = *(const bf16x8*)&es[rl * 72 + ch * 8];
      *(bf16x8*)&dst[g0 + 8 * 1024] = *(const bf16x8*)&es[(rl + 8) * 72 + ch * 8];
    }
  } else {
    // V^T: Vt[(b*16+h)*64 + d][t]
    const int b = m0 >> 11;
    const size_t hb = (size_t)(b * 16 + h) * 64;
    const int tt = (m0 + wm) & 2047;
    for (int nt = 0; nt < 4; ++nt) {
      for (int mt = 0; mt < 4; ++mt)
        for (int r = 0; r < 4; ++r)
          es[l16 * 72 + mt * 16 + 4 * quad + r] = (__bf16)acc[mt][nt][r];
      size_t g0 = (hb + nt * 16 + rl) * 2048 + tt + ch * 8;
      *(bf16x8*)&Vt[g0]                     = *(const bf16x8*)&es[rl * 72 + ch * 8];
      *(bf16x8*)&Vt[g0 + (size_t)8 * 2048]  = *(const bf16x8*)&es[(rl + 8) * 72 + ch * 8];
    }
  }
}

// ---------------------------------------------------------------------------
// Flash attention (causal). UNCHANGED from R21 (32x32 MFMA, in-reg P,
// GLDS16 swizzled staging, fixed-shift softmax, LPT+XCD grid 1024).
// ---------------------------------------------------------------------------
__global__ __launch_bounds__(256) void attn_fwd(
    __bf16* QA, const __bf16* __restrict__ Kp,
    const __bf16* __restrict__ Vt)
{
  __shared__ __bf16 Ks[2][64 * 64];   // [buf][kpos][d]  (XOR col swizzle)
  __shared__ __bf16 Vs[2][64 * 64];   // [buf][d][kpos]  (XOR col swizzle)

  const int tid  = threadIdx.x;
  const int lane = tid & 63, wid = tid >> 6;
  const int hl = lane >> 5, lq = lane & 31, lq7 = lq & 7;
  const int qh = wid & 1, kh = wid >> 1;

  const int L  = blockIdx.x;
  const int j  = L >> 3;
  const int qb = 31 - (j >> 2);
  const int bh = (L & 7) * 4 + (j & 3);
  const int b = bh >> 4, h = bh & 15;
  const int q0 = qb * 64;

  const size_t rowb = (size_t)b * 2048;
  const __bf16* Vb = Vt + (size_t)bh * 64 * 2048;

  const int srow = lane >> 3;
  const int scol = ((lane & 7) ^ srow) * 8;
  const int ck0 = wid * 2, ck1 = wid * 2 + 1;

  const int iql = qh * 32 + lq;

  bf16x8 qa[4];
#pragma unroll
  for (int ks = 0; ks < 4; ++ks)
    qa[ks] = *(const bf16x8*)
        &QA[(rowb + q0 + iql) * 1024 + h * 64 + ks * 16 + hl * 8];

  f32x16 oacc[2];
#pragma unroll
  for (int dt = 0; dt < 2; ++dt)
#pragma unroll
    for (int r = 0; r < 16; ++r) oacc[dt][r] = 0.f;
  float l_i = 0.f;

  const int kcmax = qb;

  GLDS16(Kp + (rowb + ck0 * 8 + srow) * 1024 + h * 64 + scol, &Ks[0][ck0 * 512]);
  GLDS16(Kp + (rowb + ck1 * 8 + srow) * 1024 + h * 64 + scol, &Ks[0][ck1 * 512]);
  GLDS16(Vb + (size_t)(ck0 * 8 + srow) * 2048 + scol, &Vs[0][ck0 * 512]);
  GLDS16(Vb + (size_t)(ck1 * 8 + srow) * 2048 + scol, &Vs[0][ck1 * 512]);
  __syncthreads();

  for (int kc = 0; kc <= kcmax; ++kc) {
    const int c = kc & 1;
    if (kc < kcmax) {
      const int t0 = (kc + 1) * 64;
      GLDS16(Kp + (rowb + t0 + ck0 * 8 + srow) * 1024 + h * 64 + scol,
             &Ks[c ^ 1][ck0 * 512]);
      GLDS16(Kp + (rowb + t0 + ck1 * 8 + srow) * 1024 + h * 64 + scol,
             &Ks[c ^ 1][ck1 * 512]);
      GLDS16(Vb + (size_t)(ck0 * 8 + srow) * 2048 + t0 + scol,
             &Vs[c ^ 1][ck0 * 512]);
      GLDS16(Vb + (size_t)(ck1 * 8 + srow) * 2048 + t0 + scol,
             &Vs[c ^ 1][ck1 * 512]);
    }

    const __bf16* Ksb = Ks[c];
    const __bf16* Vsb = Vs[c];

    f32x16 sacc;
#pragma unroll
    for (int r = 0; r < 16; ++r) sacc[r] = -16.f;
    __builtin_amdgcn_s_setprio(1);
#pragma unroll
    for (int ks = 0; ks < 4; ++ks) {
      bf16x8 kf = *(const bf16x8*)
          &Ksb[(kh * 32 + lq) * 64 + (((2 * ks + hl) ^ lq7) * 8)];
      sacc = __builtin_amdgcn_mfma_f32_32x32x16_bf16(kf, qa[ks], sacc, 0, 0, 0);
    }
    __builtin_amdgcn_s_setprio(0);

    const bool diag = (kc == kcmax);
    float p[16];
    float rsum = 0.f;
#pragma unroll
    for (int r = 0; r < 16; ++r) {
      float s = sacc[r];
      if (diag) {
        int kp = kh * 32 + (r & 3) + 8 * (r >> 2) + 4 * hl;
        if (kp > iql) s = -1e30f;
      }
      p[r] = __builtin_amdgcn_exp2f(s);
      rsum += p[r];
    }
    rsum += __shfl_xor(rsum, 32, 64);
    l_i += rsum;

    unsigned int cpk[8];
#pragma unroll
    for (int i = 0; i < 8; ++i)
      asm("v_cvt_pk_bf16_f32 %0, %1, %2"
          : "=v"(cpk[i]) : "v"(p[2 * i]), "v"(p[2 * i + 1]));
    bf16x8 pb[2];
#pragma unroll
    for (int k2 = 0; k2 < 2; ++k2) {
      unsigned int a0 = cpk[4 * k2 + 0], b0 = cpk[4 * k2 + 2];
      unsigned int a1 = cpk[4 * k2 + 1], b1 = cpk[4 * k2 + 3];
      asm("v_permlane32_swap_b32 %0, %1" : "+v"(a0), "+v"(b0));
      asm("v_permlane32_swap_b32 %0, %1" : "+v"(a1), "+v"(b1));
      union { unsigned int w[4]; bf16x8 v; } u;
      u.w[0] = a0; u.w[1] = a1; u.w[2] = b0; u.w[3] = b1;
      pb[k2] = u.v;
    }

    __builtin_amdgcn_s_setprio(1);
#pragma unroll
    for (int dt = 0; dt < 2; ++dt)
#pragma unroll
      for (int k2 = 0; k2 < 2; ++k2) {
        bf16x8 vf = *(const bf16x8*)
            &Vsb[(dt * 32 + lq) * 64 + (((4 * kh + 2 * k2 + hl) ^ lq7) * 8)];
        oacc[dt] = __builtin_amdgcn_mfma_f32_32x32x16_bf16(
            vf, pb[k2], oacc[dt], 0, 0, 0);
      }
    __builtin_amdgcn_s_setprio(0);

    __syncthreads();
  }

  float* Osf = (float*)&Ks[0][0];
  float* Lsf = (float*)&Vs[0][0];
  if (kh == 1) {
#pragma unroll
    for (int dt = 0; dt < 2; ++dt) {
      float* base = &Osf[((qh * 2 + dt) * 64 + lane) * 16];
#pragma unroll
      for (int g = 0; g < 4; ++g) {
        f32x4 w = {oacc[dt][4 * g], oacc[dt][4 * g + 1],
                   oacc[dt][4 * g + 2], oacc[dt][4 * g + 3]};
        *(f32x4*)&base[4 * g] = w;
      }
    }
    Lsf[qh * 64 + lane] = l_i;
  }
  __syncthreads();
  if (kh == 0) {
#pragma unroll
    for (int dt = 0; dt < 2; ++dt) {
      const float* base = &Osf[((qh * 2 + dt) * 64 + lane) * 16];
#pragma unroll
      for (int g = 0; g < 4; ++g) {
        f32x4 w = *(const f32x4*)&base[4 * g];
#pragma unroll
        for (int e = 0; e < 4; ++e) oacc[dt][4 * g + e] += w[e];
      }
    }
    float inv = 1.0f / (l_i + Lsf[qh * 64 + lane]);
#pragma unroll
    for (int dt = 0; dt < 2; ++dt)
#pragma unroll
      for (int g = 0; g < 4; ++g) {
        float a = oacc[dt][4 * g]     * inv, bb = oacc[dt][4 * g + 1] * inv;
        float cc = oacc[dt][4 * g + 2] * inv, dd = oacc[dt][4 * g + 3] * inv;
        unsigned int w0, w1;
        asm("v_cvt_pk_bf16_f32 %0, %1, %2" : "=v"(w0) : "v"(a), "v"(bb));
        asm("v_cvt_pk_bf16_f32 %0, %1, %2" : "=v"(w1) : "v"(cc), "v"(dd));
        u32x2 wv = {w0, w1};
        *(u32x2*)&QA[(rowb + q0 + iql) * 1024 + h * 64 + dt * 32 + 8 * g + 4 * hl] = wv;
      }
  }
}

// ---------------------------------------------------------------------------
// Output GEMM: out[m][n] = sum_k AO[m][k]*Wo[n][k], fp32 out. BK=64, swizzled
// GLDS16 source, conflict-free frag reads, XCD-aware decode.
// ---------------------------------------------------------------------------
__global__ __launch_bounds__(256) void gemm_out(
    const __bf16* __restrict__ AO, const __bf16* __restrict__ Wob,
    float* __restrict__ Of)
{
  __shared__ __bf16 As[128 * 64];
  __shared__ __bf16 Bs[128 * 64];
  __shared__ float  EsF[4 * 16 * 68];

  const int tid  = threadIdx.x;
  const int lane = tid & 63;
  const int wid  = tid >> 6;
  const int quad = lane >> 4;
  const int l16  = lane & 15;
  const int wm   = (wid >> 1) * 64;
  const int wn   = (wid & 1) * 64;

  // XCD decode: xcd=L&7 owns 4 m-panels x all 8 n-tiles.
  const int L  = blockIdx.x;            // 256 blocks
  const int t  = L >> 3;                // 0..31
  const int n0 = (t & 7) * 128;
  const int m0 = ((L & 7) * 4 + (t >> 3)) * 128;

  const int sr  = tid >> 3;
  const int scx = ((tid & 7) ^ (sr & 7)) * 8;
  const int fx  = l16 & 7;

  f32x4 acc[4][4];
  for (int i = 0; i < 4; ++i)
    for (int j = 0; j < 4; ++j) acc[i][j] = zero4();

  for (int k0 = 0; k0 < 1024; k0 += 64) {
    __syncthreads();
#pragma unroll
    for (int c = 0; c < 4; ++c) {
      GLDS16(AO  + (size_t)(m0 + c * 32 + sr) * 1024 + k0 + scx,
             &As[c * 2048 + (size_t)tid * 8]);
      GLDS16(Wob + (size_t)(n0 + c * 32 + sr) * 1024 + k0 + scx,
             &Bs[c * 2048 + (size_t)tid * 8]);
    }
    __syncthreads();

#pragma unroll
    for (int ks = 0; ks < 2; ++ks) {
      bf16x8 af[4], bfr[4];
#pragma unroll
      for (int i = 0; i < 4; ++i)
        af[i] = *(const bf16x8*)
            &As[(wm + i * 16 + l16) * 64 + ((ks * 4 + quad) ^ fx) * 8];
#pragma unroll
      for (int i = 0; i < 4; ++i)
        bfr[i] = *(const bf16x8*)
            &Bs[(wn + i * 16 + l16) * 64 + ((ks * 4 + quad) ^ fx) * 8];
#pragma unroll
      for (int mt = 0; mt < 4; ++mt)
#pragma unroll
        for (int nt = 0; nt < 4; ++nt)
          acc[mt][nt] = __builtin_amdgcn_mfma_f32_16x16x32_bf16(
              af[mt], bfr[nt], acc[mt][nt], 0, 0, 0);
    }
  }

  float* es = &EsF[wid * 1088];         // 16 x 68 f32, per-wave private
  const int rl = lane >> 4, ch = lane & 15;
  for (int mt = 0; mt < 4; ++mt) {
    for (int nt = 0; nt < 4; ++nt)
      for (int r = 0; r < 4; ++r)
        es[(4 * quad + r) * 68 + nt * 16 + l16] = acc[mt][nt][r];
    size_t g0 = (size_t)(m0 + wm + mt * 16 + rl) * 1024 + n0 + wn + ch * 4;
    *(f32x4*)&Of[g0]             = *(const f32x4*)&es[rl * 68 + ch * 4];
    *(f32x4*)&Of[g0 + 4 * 1024]  = *(const f32x4*)&es[(rl + 4) * 68 + ch * 4];
    *(f32x4*)&Of[g0 + 8 * 1024]  = *(const f32x4*)&es[(rl + 8) * 68 + ch * 4];
    *(f32x4*)&Of[g0 + 12 * 1024] = *(const f32x4*)&es[(rl + 12) * 68 + ch * 4];
  }
}

// copy 8 bf16/lane
__global__ __launch_bounds__(256) void copy_bf16x8(
    const __bf16* __restrict__ src, __bf16* __restrict__ dst)
{
  size_t i = ((size_t)blockIdx.x * 256 + threadIdx.x) * 8;
  *(bf16x8*)&dst[i] = *(const bf16x8*)&src[i];
}

// ---------------------------------------------------------------------------
extern "C" void kernel_launch(void* const* d_in, const int* in_sizes, int n_in,
                              void* d_out, int out_size, void* d_ws, size_t ws_size,
                              hipStream_t stream) {
  const float* x  = (const float*)d_in[0];
  const float* Wq = (const float*)d_in[1];
  const float* Wk = (const float*)d_in[2];
  const float* Wv = (const float*)d_in[3];
  const float* Wo = (const float*)d_in[4];
  float* out = (float*)d_out;

  const size_t NELT = (size_t)4194304;             // 4M elems (8 MiB bf16)
  __bf16* Qp = (__bf16*)d_ws;        // plain Q, becomes AO in-place
  __bf16* Kp = Qp + NELT;            // plain K, later holds Wo bf16
  __bf16* Vt = Kp + NELT;            // V^T [bh][d][t]
  __bf16* xb = (__bf16*)d_out;       // d_out[0:8MB) scratch: x bf16
  __bf16* Wb = xb + NELT;            // d_out[8:16MB): W* bf16

  prep<<<dim3(4096), 256, 0, stream>>>(x, Wq, Wk, Wv, Wo, xb, Wb);
  gemm_qkv<<<dim3(768), 256, 0, stream>>>(xb, Wb, Qp, Kp, Vt);
  attn_fwd<<<dim3(1024), 256, 0, stream>>>(Qp, Kp, Vt);
  copy_bf16x8<<<dim3(512), 256, 0, stream>>>(Wb + 3 * NELT / 4, Kp);
  gemm_out<<<dim3(256), 256, 0, stream>>>(Qp, Kp, out);
}

// Round 11
// 194.692 us; speedup vs baseline: 1.0117x; 1.0117x over previous
//
#include <hip/hip_runtime.h>
#include <stdint.h>

// MultiHeadAttention w/ RoPE, causal. B=2, T=2048, C=1024, H=16, Dh=64.
// Round 23: GEMM fix-forward from R22 regression.
//  R22 counters: swizzle worked (conflicts 3.3M->164K, KEEP) but (a) new XCD
//  decode duplicated B across XCDs (FETCH 35.9->54.3MB) and (b) LDS 42KB
//  halved occupancy (26->13.7%). Fixes: revert decode to n0=(L&7)*128 (B
//  n-column per XCD, A-panels via L3 -- the R21 arrangement that measured
//  35.9MB), and overlay the epilogue transpose buffer onto As/Bs (dead after
//  k-loop; one barrier) -> LDS 32.8KB, 5 blocks/CU. BK=64 kept.
//  attn_fwd unchanged (R21). Same treatment in gemm_out.

typedef float  f32x4  __attribute__((ext_vector_type(4)));
typedef float  f32x16 __attribute__((ext_vector_type(16)));
typedef __bf16 bf16x8 __attribute__((ext_vector_type(8)));
typedef unsigned int u32x2 __attribute__((ext_vector_type(2)));

#define GLDS16(gp, lp)                                                         \
  __builtin_amdgcn_global_load_lds(                                            \
      (const __attribute__((address_space(1))) void*)(gp),                     \
      (__attribute__((address_space(3))) void*)(lp), 16, 0, 0)

static __device__ __forceinline__ f32x4 zero4() {
  f32x4 z = {0.f, 0.f, 0.f, 0.f};
  return z;
}

static __device__ __forceinline__ bf16x8 cvt8(const float* __restrict__ p) {
  f32x4 u = *(const f32x4*)p;
  f32x4 v = *(const f32x4*)(p + 4);
  bf16x8 o;
#pragma unroll
  for (int j = 0; j < 4; ++j) o[j] = (__bf16)u[j];
#pragma unroll
  for (int j = 0; j < 4; ++j) o[4 + j] = (__bf16)v[j];
  return o;
}

// ---------------------------------------------------------------------------
// Prepass: x (4M f32) -> xb bf16; Wq/Wk/Wv/Wo (1M f32 each) -> Wb bf16[4][1M].
// ---------------------------------------------------------------------------
__global__ __launch_bounds__(256) void prep(
    const float* __restrict__ x,
    const float* __restrict__ Wq, const float* __restrict__ Wk,
    const float* __restrict__ Wv, const float* __restrict__ Wo,
    __bf16* __restrict__ xb, __bf16* __restrict__ Wb)
{
  size_t g = ((size_t)blockIdx.x * 256 + threadIdx.x) * 8;
  if (g < (size_t)4194304) {
    *(bf16x8*)&xb[g] = cvt8(x + g);
  } else {
    size_t j = g - 4194304;
    int w = (int)(j >> 20);
    size_t off = j & 1048575;
    const float* src = (w == 0) ? Wq : (w == 1) ? Wk : (w == 2) ? Wv : Wo;
    *(bf16x8*)&Wb[(size_t)w * 1048576 + off] = cvt8(src + off);
  }
}

// ---------------------------------------------------------------------------
// QKV GEMM: C[m][n] = sum_k xb[m][k]*W[n][k]. 128x128 tile, BK=64, GLDS16
// with pre-swizzled source col; conflict-free frag reads. Decode: n-column
// tied to XCD (L&7); A-panels shared via L3. Epilogue tiles overlay As/Bs.
// z<2: RoPE fused (Q pre-scaled by 0.125*log2e). z=2: V^T [bh][d][t].
// ---------------------------------------------------------------------------
__global__ __launch_bounds__(256) void gemm_qkv(
    const __bf16* __restrict__ xb, const __bf16* __restrict__ Wb,
    __bf16* __restrict__ Qp, __bf16* __restrict__ Kp, __bf16* __restrict__ Vt)
{
  __shared__ __bf16 Smem[2 * 128 * 64];   // As | Bs ; epilogue Es overlays
  __bf16* As = Smem;
  __bf16* Bs = Smem + 128 * 64;

  const int tid  = threadIdx.x;
  const int lane = tid & 63;
  const int wid  = tid >> 6;
  const int quad = lane >> 4;
  const int l16  = lane & 15;
  const int wm   = (wid >> 1) * 64;
  const int wn   = (wid & 1) * 64;

  // R21 decode: n0 tied to XCD (L&7) -> B n-column per XCD; A via L3.
  const int lin = blockIdx.x;           // 768 blocks
  const int n0  = (lin & 7) * 128;
  const int r2  = lin >> 3;
  const int z   = r2 % 3;
  const int m0  = (r2 / 3) * 128;
  const __bf16* Bt = Wb + (size_t)z * 1048576;

  const int sr  = tid >> 3;             // 0..31 staging row within chunk
  const int scx = ((tid & 7) ^ (sr & 7)) * 8;  // pre-swizzled source col
  const int fx  = l16 & 7;              // frag-read xor term

  f32x4 acc[4][4];
  for (int i = 0; i < 4; ++i)
    for (int j = 0; j < 4; ++j) acc[i][j] = zero4();

  for (int k0 = 0; k0 < 1024; k0 += 64) {
    __syncthreads();
#pragma unroll
    for (int c = 0; c < 4; ++c) {
      GLDS16(xb + (size_t)(m0 + c * 32 + sr) * 1024 + k0 + scx,
             &As[c * 2048 + (size_t)tid * 8]);
      GLDS16(Bt + (size_t)(n0 + c * 32 + sr) * 1024 + k0 + scx,
             &Bs[c * 2048 + (size_t)tid * 8]);
    }
    __syncthreads();

#pragma unroll
    for (int ks = 0; ks < 2; ++ks) {
      bf16x8 af[4], bfr[4];
#pragma unroll
      for (int i = 0; i < 4; ++i)
        af[i] = *(const bf16x8*)
            &As[(wm + i * 16 + l16) * 64 + ((ks * 4 + quad) ^ fx) * 8];
#pragma unroll
      for (int i = 0; i < 4; ++i)
        bfr[i] = *(const bf16x8*)
            &Bs[(wn + i * 16 + l16) * 64 + ((ks * 4 + quad) ^ fx) * 8];
#pragma unroll
      for (int mt = 0; mt < 4; ++mt)
#pragma unroll
        for (int nt = 0; nt < 4; ++nt)
          acc[mt][nt] = __builtin_amdgcn_mfma_f32_16x16x32_bf16(
              af[mt], bfr[nt], acc[mt][nt], 0, 0, 0);
    }
  }

  __syncthreads();   // all As/Bs reads done; safe to overlay epilogue tiles

  // D layout: row = 4*quad + reg, col = l16 per 16x16 subtile.
  const int h = (n0 + wn) >> 6;
  __bf16* es = &Smem[wid * 1152];      // 16 x 72, per-wave private (overlay)
  const int rl = lane >> 3, ch = lane & 7;

  if (z < 2) {
    // fused RoPE; for Q (z==0) fold softmax scale 0.125*log2(e) into cv/sv.
    const float c0f = -13.287712379549449f / 32.0f;  // -log2(10000)/32
    const float f0 = exp2f((float)l16 * c0f);
    const float f1 = exp2f((float)(16 + l16) * c0f);
    const float SC = (z == 0) ? 0.125f * 1.44269504088896340736f : 1.0f;
    for (int mt = 0; mt < 4; ++mt)
      for (int r = 0; r < 4; ++r) {
        int gm = m0 + wm + mt * 16 + 4 * quad + r;
        float tt = (float)(gm & 2047);
        for (int nt = 0; nt < 2; ++nt) {
          float ang = tt * (nt ? f1 : f0);
          float cv = __cosf(ang) * SC, sv = __sinf(ang) * SC;
          float lo = acc[mt][nt][r], hi = acc[mt][nt + 2][r];
          acc[mt][nt][r]     = lo * cv - hi * sv;
          acc[mt][nt + 2][r] = hi * cv + lo * sv;
        }
      }
    __bf16* dst = (z == 0) ? Qp : Kp;
    for (int mt = 0; mt < 4; ++mt) {
      for (int nt = 0; nt < 4; ++nt)
        for (int r = 0; r < 4; ++r)
          es[(4 * quad + r) * 72 + nt * 16 + l16] = (__bf16)acc[mt][nt][r];
      size_t g0 = (size_t)(m0 + wm + mt * 16 + rl) * 1024 + n0 + wn + ch * 8;
      *(bf16x8*)&dst[g0]            = *(const bf16x8*)&es[rl * 72 + ch * 8];
      *(bf16x8*)&dst[g0 + 8 * 1024] = *(const bf16x8*)&es[(rl + 8) * 72 + ch * 8];
    }
  } else {
    // V^T: Vt[(b*16+h)*64 + d][t]
    const int b = m0 >> 11;
    const size_t hb = (size_t)(b * 16 + h) * 64;
    const int tt = (m0 + wm) & 2047;
    for (int nt = 0; nt < 4; ++nt) {
      for (int mt = 0; mt < 4; ++mt)
        for (int r = 0; r < 4; ++r)
          es[l16 * 72 + mt * 16 + 4 * quad + r] = (__bf16)acc[mt][nt][r];
      size_t g0 = (hb + nt * 16 + rl) * 2048 + tt + ch * 8;
      *(bf16x8*)&Vt[g0]                     = *(const bf16x8*)&es[rl * 72 + ch * 8];
      *(bf16x8*)&Vt[g0 + (size_t)8 * 2048]  = *(const bf16x8*)&es[(rl + 8) * 72 + ch * 8];
    }
  }
}

// ---------------------------------------------------------------------------
// Flash attention (causal). UNCHANGED from R21 (32x32 MFMA, in-reg P,
// GLDS16 swizzled staging, fixed-shift softmax, LPT+XCD grid 1024).
// ---------------------------------------------------------------------------
__global__ __launch_bounds__(256) void attn_fwd(
    __bf16* QA, const __bf16* __restrict__ Kp,
    const __bf16* __restrict__ Vt)
{
  __shared__ __bf16 Ks[2][64 * 64];   // [buf][kpos][d]  (XOR col swizzle)
  __shared__ __bf16 Vs[2][64 * 64];   // [buf][d][kpos]  (XOR col swizzle)

  const int tid  = threadIdx.x;
  const int lane = tid & 63, wid = tid >> 6;
  const int hl = lane >> 5, lq = lane & 31, lq7 = lq & 7;
  const int qh = wid & 1, kh = wid >> 1;

  const int L  = blockIdx.x;
  const int j  = L >> 3;
  const int qb = 31 - (j >> 2);
  const int bh = (L & 7) * 4 + (j & 3);
  const int b = bh >> 4, h = bh & 15;
  const int q0 = qb * 64;

  const size_t rowb = (size_t)b * 2048;
  const __bf16* Vb = Vt + (size_t)bh * 64 * 2048;

  const int srow = lane >> 3;
  const int scol = ((lane & 7) ^ srow) * 8;
  const int ck0 = wid * 2, ck1 = wid * 2 + 1;

  const int iql = qh * 32 + lq;

  bf16x8 qa[4];
#pragma unroll
  for (int ks = 0; ks < 4; ++ks)
    qa[ks] = *(const bf16x8*)
        &QA[(rowb + q0 + iql) * 1024 + h * 64 + ks * 16 + hl * 8];

  f32x16 oacc[2];
#pragma unroll
  for (int dt = 0; dt < 2; ++dt)
#pragma unroll
    for (int r = 0; r < 16; ++r) oacc[dt][r] = 0.f;
  float l_i = 0.f;

  const int kcmax = qb;

  GLDS16(Kp + (rowb + ck0 * 8 + srow) * 1024 + h * 64 + scol, &Ks[0][ck0 * 512]);
  GLDS16(Kp + (rowb + ck1 * 8 + srow) * 1024 + h * 64 + scol, &Ks[0][ck1 * 512]);
  GLDS16(Vb + (size_t)(ck0 * 8 + srow) * 2048 + scol, &Vs[0][ck0 * 512]);
  GLDS16(Vb + (size_t)(ck1 * 8 + srow) * 2048 + scol, &Vs[0][ck1 * 512]);
  __syncthreads();

  for (int kc = 0; kc <= kcmax; ++kc) {
    const int c = kc & 1;
    if (kc < kcmax) {
      const int t0 = (kc + 1) * 64;
      GLDS16(Kp + (rowb + t0 + ck0 * 8 + srow) * 1024 + h * 64 + scol,
             &Ks[c ^ 1][ck0 * 512]);
      GLDS16(Kp + (rowb + t0 + ck1 * 8 + srow) * 1024 + h * 64 + scol,
             &Ks[c ^ 1][ck1 * 512]);
      GLDS16(Vb + (size_t)(ck0 * 8 + srow) * 2048 + t0 + scol,
             &Vs[c ^ 1][ck0 * 512]);
      GLDS16(Vb + (size_t)(ck1 * 8 + srow) * 2048 + t0 + scol,
             &Vs[c ^ 1][ck1 * 512]);
    }

    const __bf16* Ksb = Ks[c];
    const __bf16* Vsb = Vs[c];

    f32x16 sacc;
#pragma unroll
    for (int r = 0; r < 16; ++r) sacc[r] = -16.f;
    __builtin_amdgcn_s_setprio(1);
#pragma unroll
    for (int ks = 0; ks < 4; ++ks) {
      bf16x8 kf = *(const bf16x8*)
          &Ksb[(kh * 32 + lq) * 64 + (((2 * ks + hl) ^ lq7) * 8)];
      sacc = __builtin_amdgcn_mfma_f32_32x32x16_bf16(kf, qa[ks], sacc, 0, 0, 0);
    }
    __builtin_amdgcn_s_setprio(0);

    const bool diag = (kc == kcmax);
    float p[16];
    float rsum = 0.f;
#pragma unroll
    for (int r = 0; r < 16; ++r) {
      float s = sacc[r];
      if (diag) {
        int kp = kh * 32 + (r & 3) + 8 * (r >> 2) + 4 * hl;
        if (kp > iql) s = -1e30f;
      }
      p[r] = __builtin_amdgcn_exp2f(s);
      rsum += p[r];
    }
    rsum += __shfl_xor(rsum, 32, 64);
    l_i += rsum;

    unsigned int cpk[8];
#pragma unroll
    for (int i = 0; i < 8; ++i)
      asm("v_cvt_pk_bf16_f32 %0, %1, %2"
          : "=v"(cpk[i]) : "v"(p[2 * i]), "v"(p[2 * i + 1]));
    bf16x8 pb[2];
#pragma unroll
    for (int k2 = 0; k2 < 2; ++k2) {
      unsigned int a0 = cpk[4 * k2 + 0], b0 = cpk[4 * k2 + 2];
      unsigned int a1 = cpk[4 * k2 + 1], b1 = cpk[4 * k2 + 3];
      asm("v_permlane32_swap_b32 %0, %1" : "+v"(a0), "+v"(b0));
      asm("v_permlane32_swap_b32 %0, %1" : "+v"(a1), "+v"(b1));
      union { unsigned int w[4]; bf16x8 v; } u;
      u.w[0] = a0; u.w[1] = a1; u.w[2] = b0; u.w[3] = b1;
      pb[k2] = u.v;
    }

    __builtin_amdgcn_s_setprio(1);
#pragma unroll
    for (int dt = 0; dt < 2; ++dt)
#pragma unroll
      for (int k2 = 0; k2 < 2; ++k2) {
        bf16x8 vf = *(const bf16x8*)
            &Vsb[(dt * 32 + lq) * 64 + (((4 * kh + 2 * k2 + hl) ^ lq7) * 8)];
        oacc[dt] = __builtin_amdgcn_mfma_f32_32x32x16_bf16(
            vf, pb[k2], oacc[dt], 0, 0, 0);
      }
    __builtin_amdgcn_s_setprio(0);

    __syncthreads();
  }

  float* Osf = (float*)&Ks[0][0];
  float* Lsf = (float*)&Vs[0][0];
  if (kh == 1) {
#pragma unroll
    for (int dt = 0; dt < 2; ++dt) {
      float* base = &Osf[((qh * 2 + dt) * 64 + lane) * 16];
#pragma unroll
      for (int g = 0; g < 4; ++g) {
        f32x4 w = {oacc[dt][4 * g], oacc[dt][4 * g + 1],
                   oacc[dt][4 * g + 2], oacc[dt][4 * g + 3]};
        *(f32x4*)&base[4 * g] = w;
      }
    }
    Lsf[qh * 64 + lane] = l_i;
  }
  __syncthreads();
  if (kh == 0) {
#pragma unroll
    for (int dt = 0; dt < 2; ++dt) {
      const float* base = &Osf[((qh * 2 + dt) * 64 + lane) * 16];
#pragma unroll
      for (int g = 0; g < 4; ++g) {
        f32x4 w = *(const f32x4*)&base[4 * g];
#pragma unroll
        for (int e = 0; e < 4; ++e) oacc[dt][4 * g + e] += w[e];
      }
    }
    float inv = 1.0f / (l_i + Lsf[qh * 64 + lane]);
#pragma unroll
    for (int dt = 0; dt < 2; ++dt)
#pragma unroll
      for (int g = 0; g < 4; ++g) {
        float a = oacc[dt][4 * g]     * inv, bb = oacc[dt][4 * g + 1] * inv;
        float cc = oacc[dt][4 * g + 2] * inv, dd = oacc[dt][4 * g + 3] * inv;
        unsigned int w0, w1;
        asm("v_cvt_pk_bf16_f32 %0, %1, %2" : "=v"(w0) : "v"(a), "v"(bb));
        asm("v_cvt_pk_bf16_f32 %0, %1, %2" : "=v"(w1) : "v"(cc), "v"(dd));
        u32x2 wv = {w0, w1};
        *(u32x2*)&QA[(rowb + q0 + iql) * 1024 + h * 64 + dt * 32 + 8 * g + 4 * hl] = wv;
      }
  }
}

// ---------------------------------------------------------------------------
// Output GEMM: out[m][n] = sum_k AO[m][k]*Wo[n][k], fp32 out. BK=64, swizzled
// GLDS16 source, conflict-free frag reads, n-column per XCD, overlay epilogue.
// ---------------------------------------------------------------------------
__global__ __launch_bounds__(256) void gemm_out(
    const __bf16* __restrict__ AO, const __bf16* __restrict__ Wob,
    float* __restrict__ Of)
{
  __shared__ __bf16 Smem[2 * 128 * 64];   // As | Bs ; epilogue EsF overlays
  __bf16* As = Smem;
  __bf16* Bs = Smem + 128 * 64;

  const int tid  = threadIdx.x;
  const int lane = tid & 63;
  const int wid  = tid >> 6;
  const int quad = lane >> 4;
  const int l16  = lane & 15;
  const int wm   = (wid >> 1) * 64;
  const int wn   = (wid & 1) * 64;

  const int lin = blockIdx.x;           // 256 blocks
  const int n0  = (lin & 7) * 128;
  const int m0  = (lin >> 3) * 128;

  const int sr  = tid >> 3;
  const int scx = ((tid & 7) ^ (sr & 7)) * 8;
  const int fx  = l16 & 7;

  f32x4 acc[4][4];
  for (int i = 0; i < 4; ++i)
    for (int j = 0; j < 4; ++j) acc[i][j] = zero4();

  for (int k0 = 0; k0 < 1024; k0 += 64) {
    __syncthreads();
#pragma unroll
    for (int c = 0; c < 4; ++c) {
      GLDS16(AO  + (size_t)(m0 + c * 32 + sr) * 1024 + k0 + scx,
             &As[c * 2048 + (size_t)tid * 8]);
      GLDS16(Wob + (size_t)(n0 + c * 32 + sr) * 1024 + k0 + scx,
             &Bs[c * 2048 + (size_t)tid * 8]);
    }
    __syncthreads();

#pragma unroll
    for (int ks = 0; ks < 2; ++ks) {
      bf16x8 af[4], bfr[4];
#pragma unroll
      for (int i = 0; i < 4; ++i)
        af[i] = *(const bf16x8*)
            &As[(wm + i * 16 + l16) * 64 + ((ks * 4 + quad) ^ fx) * 8];
#pragma unroll
      for (int i = 0; i < 4; ++i)
        bfr[i] = *(const bf16x8*)
            &Bs[(wn + i * 16 + l16) * 64 + ((ks * 4 + quad) ^ fx) * 8];
#pragma unroll
      for (int mt = 0; mt < 4; ++mt)
#pragma unroll
        for (int nt = 0; nt < 4; ++nt)
          acc[mt][nt] = __builtin_amdgcn_mfma_f32_16x16x32_bf16(
              af[mt], bfr[nt], acc[mt][nt], 0, 0, 0);
    }
  }

  __syncthreads();   // As/Bs dead; overlay f32 transpose tiles

  float* es = (float*)&Smem[0] + wid * 1088;   // 16 x 68 f32, per-wave
  const int rl = lane >> 4, ch = lane & 15;
  for (int mt = 0; mt < 4; ++mt) {
    for (int nt = 0; nt < 4; ++nt)
      for (int r = 0; r < 4; ++r)
        es[(4 * quad + r) * 68 + nt * 16 + l16] = acc[mt][nt][r];
    size_t g0 = (size_t)(m0 + wm + mt * 16 + rl) * 1024 + n0 + wn + ch * 4;
    *(f32x4*)&Of[g0]             = *(const f32x4*)&es[rl * 68 + ch * 4];
    *(f32x4*)&Of[g0 + 4 * 1024]  = *(const f32x4*)&es[(rl + 4) * 68 + ch * 4];
    *(f32x4*)&Of[g0 + 8 * 1024]  = *(const f32x4*)&es[(rl + 8) * 68 + ch * 4];
    *(f32x4*)&Of[g0 + 12 * 1024] = *(const f32x4*)&es[(rl + 12) * 68 + ch * 4];
  }
}

// copy 8 bf16/lane
__global__ __launch_bounds__(256) void copy_bf16x8(
    const __bf16* __restrict__ src, __bf16* __restrict__ dst)
{
  size_t i = ((size_t)blockIdx.x * 256 + threadIdx.x) * 8;
  *(bf16x8*)&dst[i] = *(const bf16x8*)&src[i];
}

// ---------------------------------------------------------------------------
extern "C" void kernel_launch(void* const* d_in, const int* in_sizes, int n_in,
                              void* d_out, int out_size, void* d_ws, size_t ws_size,
                              hipStream_t stream) {
  const float* x  = (const float*)d_in[0];
  const float* Wq = (const float*)d_in[1];
  const float* Wk = (const float*)d_in[2];
  const float* Wv = (const float*)d_in[3];
  const float* Wo = (const float*)d_in[4];
  float* out = (float*)d_out;

  const size_t NELT = (size_t)4194304;             // 4M elems (8 MiB bf16)
  __bf16* Qp = (__bf16*)d_ws;        // plain Q, becomes AO in-place
  __bf16* Kp = Qp + NELT;            // plain K, later holds Wo bf16
  __bf16* Vt = Kp + NELT;            // V^T [bh][d][t]
  __bf16* xb = (__bf16*)d_out;       // d_out[0:8MB) scratch: x bf16
  __bf16* Wb = xb + NELT;            // d_out[8:16MB): W* bf16

  prep<<<dim3(4096), 256, 0, stream>>>(x, Wq, Wk, Wv, Wo, xb, Wb);
  gemm_qkv<<<dim3(768), 256, 0, stream>>>(xb, Wb, Qp, Kp, Vt);
  attn_fwd<<<dim3(1024), 256, 0, stream>>>(Qp, Kp, Vt);
  copy_bf16x8<<<dim3(512), 256, 0, stream>>>(Wb + 3 * NELT / 4, Kp);
  gemm_out<<<dim3(256), 256, 0, stream>>>(Qp, Kp, out);
}

// Round 12
// 184.741 us; speedup vs baseline: 1.0662x; 1.0539x over previous
//
#include <hip/hip_runtime.h>
#include <stdint.h>

// MultiHeadAttention w/ RoPE, causal. B=2, T=2048, C=1024, H=16, Dh=64.
// Round 24: GEMMs back to BK=32 (R21-proven) + swizzle + overlay; gemm_out
// occupancy fix.
//  R23 verdict: BK=64 is a net loss (barrier drain batch doubled, occupancy
//  14.6% vs 26%); swizzle + n0-per-XCD decode are wins. This round:
//  (a) BK=32 k-loop cadence (44.4us proven) with swizzle adapted:
//      LDS[r][c] = G[r][c^((r>>1)&3)], frag chunk = quad^((l16>>1)&3)
//      -> uniform bank spread, 2 lanes/bank-group = free.
//  (b) Es overlay onto As/Bs: gemm_qkv LDS 16.4KB.
//  (c) gemm_out was 256 blocks = 1 block/CU (4 waves) -> re-tiled 64x128,
//      512 blocks, 2/CU, BK=32 + swizzle, overlay (17.4KB).
//  attn_fwd unchanged (R21).

typedef float  f32x4  __attribute__((ext_vector_type(4)));
typedef float  f32x16 __attribute__((ext_vector_type(16)));
typedef __bf16 bf16x8 __attribute__((ext_vector_type(8)));
typedef unsigned int u32x2 __attribute__((ext_vector_type(2)));

#define GLDS16(gp, lp)                                                         \
  __builtin_amdgcn_global_load_lds(                                            \
      (const __attribute__((address_space(1))) void*)(gp),                     \
      (__attribute__((address_space(3))) void*)(lp), 16, 0, 0)

static __device__ __forceinline__ f32x4 zero4() {
  f32x4 z = {0.f, 0.f, 0.f, 0.f};
  return z;
}

static __device__ __forceinline__ bf16x8 cvt8(const float* __restrict__ p) {
  f32x4 u = *(const f32x4*)p;
  f32x4 v = *(const f32x4*)(p + 4);
  bf16x8 o;
#pragma unroll
  for (int j = 0; j < 4; ++j) o[j] = (__bf16)u[j];
#pragma unroll
  for (int j = 0; j < 4; ++j) o[4 + j] = (__bf16)v[j];
  return o;
}

// ---------------------------------------------------------------------------
// Prepass: x (4M f32) -> xb bf16; Wq/Wk/Wv/Wo (1M f32 each) -> Wb bf16[4][1M].
// ---------------------------------------------------------------------------
__global__ __launch_bounds__(256) void prep(
    const float* __restrict__ x,
    const float* __restrict__ Wq, const float* __restrict__ Wk,
    const float* __restrict__ Wv, const float* __restrict__ Wo,
    __bf16* __restrict__ xb, __bf16* __restrict__ Wb)
{
  size_t g = ((size_t)blockIdx.x * 256 + threadIdx.x) * 8;
  if (g < (size_t)4194304) {
    *(bf16x8*)&xb[g] = cvt8(x + g);
  } else {
    size_t j = g - 4194304;
    int w = (int)(j >> 20);
    size_t off = j & 1048575;
    const float* src = (w == 0) ? Wq : (w == 1) ? Wk : (w == 2) ? Wv : Wo;
    *(bf16x8*)&Wb[(size_t)w * 1048576 + off] = cvt8(src + off);
  }
}

// ---------------------------------------------------------------------------
// QKV GEMM: C[m][n] = sum_k xb[m][k]*W[n][k]. 128x128 tile, BK=32 (R21
// cadence), swizzled GLDS16 source + conflict-free frag reads, Es overlay.
// z<2: RoPE fused (Q pre-scaled by 0.125*log2e). z=2: V^T [bh][d][t].
// ---------------------------------------------------------------------------
__global__ __launch_bounds__(256) void gemm_qkv(
    const __bf16* __restrict__ xb, const __bf16* __restrict__ Wb,
    __bf16* __restrict__ Qp, __bf16* __restrict__ Kp, __bf16* __restrict__ Vt)
{
  __shared__ __bf16 Smem[2 * 128 * 32];   // As | Bs ; epilogue Es overlays
  __bf16* As = Smem;
  __bf16* Bs = Smem + 128 * 32;

  const int tid  = threadIdx.x;
  const int lane = tid & 63;
  const int wid  = tid >> 6;
  const int quad = lane >> 4;
  const int l16  = lane & 15;
  const int wm   = (wid >> 1) * 64;
  const int wn   = (wid & 1) * 64;

  // n-column tied to XCD (L&7); A-panels shared via L3 (R21/R23-verified).
  const int lin = blockIdx.x;           // 768 blocks
  const int n0  = (lin & 7) * 128;
  const int r2  = lin >> 3;
  const int z   = r2 % 3;
  const int m0  = (r2 / 3) * 128;
  const __bf16* Bt = Wb + (size_t)z * 1048576;

  const int r0 = tid >> 2, c0 = tid & 3;
  const int r1 = r0 + 64;
  // source col chunk pre-swizzled: LDS[r][c] = G[r][c ^ ((r>>1)&3)]
  const int scx = (c0 ^ ((r0 >> 1) & 3)) * 8;   // same for r1 (r1=r0+64)
  const int fq  = (l16 >> 1) & 3;               // frag-read xor term

  f32x4 acc[4][4];
  for (int i = 0; i < 4; ++i)
    for (int j = 0; j < 4; ++j) acc[i][j] = zero4();

  for (int k0 = 0; k0 < 1024; k0 += 32) {
    __syncthreads();
    GLDS16(xb + (size_t)(m0 + r0) * 1024 + k0 + scx, &As[(size_t)tid * 8]);
    GLDS16(xb + (size_t)(m0 + r1) * 1024 + k0 + scx, &As[(size_t)(tid + 256) * 8]);
    GLDS16(Bt + (size_t)(n0 + r0) * 1024 + k0 + scx, &Bs[(size_t)tid * 8]);
    GLDS16(Bt + (size_t)(n0 + r1) * 1024 + k0 + scx, &Bs[(size_t)(tid + 256) * 8]);
    __syncthreads();

    bf16x8 af[4], bfr[4];
#pragma unroll
    for (int i = 0; i < 4; ++i)
      af[i] = *(const bf16x8*)
          &As[(wm + i * 16 + l16) * 32 + ((quad ^ fq) * 8)];
#pragma unroll
    for (int i = 0; i < 4; ++i)
      bfr[i] = *(const bf16x8*)
          &Bs[(wn + i * 16 + l16) * 32 + ((quad ^ fq) * 8)];
#pragma unroll
    for (int mt = 0; mt < 4; ++mt)
#pragma unroll
      for (int nt = 0; nt < 4; ++nt)
        acc[mt][nt] = __builtin_amdgcn_mfma_f32_16x16x32_bf16(
            af[mt], bfr[nt], acc[mt][nt], 0, 0, 0);
  }

  __syncthreads();   // As/Bs dead; overlay epilogue transpose tiles

  // D layout: row = 4*quad + reg, col = l16 per 16x16 subtile.
  const int h = (n0 + wn) >> 6;
  __bf16* es = &Smem[wid * 1152];      // 16 x 72, per-wave private (overlay)
  const int rl = lane >> 3, ch = lane & 7;

  if (z < 2) {
    // fused RoPE; for Q (z==0) fold softmax scale 0.125*log2(e) into cv/sv.
    const float c0f = -13.287712379549449f / 32.0f;  // -log2(10000)/32
    const float f0 = exp2f((float)l16 * c0f);
    const float f1 = exp2f((float)(16 + l16) * c0f);
    const float SC = (z == 0) ? 0.125f * 1.44269504088896340736f : 1.0f;
    for (int mt = 0; mt < 4; ++mt)
      for (int r = 0; r < 4; ++r) {
        int gm = m0 + wm + mt * 16 + 4 * quad + r;
        float tt = (float)(gm & 2047);
        for (int nt = 0; nt < 2; ++nt) {
          float ang = tt * (nt ? f1 : f0);
          float cv = __cosf(ang) * SC, sv = __sinf(ang) * SC;
          float lo = acc[mt][nt][r], hi = acc[mt][nt + 2][r];
          acc[mt][nt][r]     = lo * cv - hi * sv;
          acc[mt][nt + 2][r] = hi * cv + lo * sv;
        }
      }
    __bf16* dst = (z == 0) ? Qp : Kp;
    for (int mt = 0; mt < 4; ++mt) {
      for (int nt = 0; nt < 4; ++nt)
        for (int r = 0; r < 4; ++r)
          es[(4 * quad + r) * 72 + nt * 16 + l16] = (__bf16)acc[mt][nt][r];
      size_t g0 = (size_t)(m0 + wm + mt * 16 + rl) * 1024 + n0 + wn + ch * 8;
      *(bf16x8*)&dst[g0]            = *(const bf16x8*)&es[rl * 72 + ch * 8];
      *(bf16x8*)&dst[g0 + 8 * 1024] = *(const bf16x8*)&es[(rl + 8) * 72 + ch * 8];
    }
  } else {
    // V^T: Vt[(b*16+h)*64 + d][t]
    const int b = m0 >> 11;
    const size_t hb = (size_t)(b * 16 + h) * 64;
    const int tt = (m0 + wm) & 2047;
    for (int nt = 0; nt < 4; ++nt) {
      for (int mt = 0; mt < 4; ++mt)
        for (int r = 0; r < 4; ++r)
          es[l16 * 72 + mt * 16 + 4 * quad + r] = (__bf16)acc[mt][nt][r];
      size_t g0 = (hb + nt * 16 + rl) * 2048 + tt + ch * 8;
      *(bf16x8*)&Vt[g0]                     = *(const bf16x8*)&es[rl * 72 + ch * 8];
      *(bf16x8*)&Vt[g0 + (size_t)8 * 2048]  = *(const bf16x8*)&es[(rl + 8) * 72 + ch * 8];
    }
  }
}

// ---------------------------------------------------------------------------
// Flash attention (causal). UNCHANGED from R21 (32x32 MFMA, in-reg P,
// GLDS16 swizzled staging, fixed-shift softmax, LPT+XCD grid 1024).
// ---------------------------------------------------------------------------
__global__ __launch_bounds__(256) void attn_fwd(
    __bf16* QA, const __bf16* __restrict__ Kp,
    const __bf16* __restrict__ Vt)
{
  __shared__ __bf16 Ks[2][64 * 64];   // [buf][kpos][d]  (XOR col swizzle)
  __shared__ __bf16 Vs[2][64 * 64];   // [buf][d][kpos]  (XOR col swizzle)

  const int tid  = threadIdx.x;
  const int lane = tid & 63, wid = tid >> 6;
  const int hl = lane >> 5, lq = lane & 31, lq7 = lq & 7;
  const int qh = wid & 1, kh = wid >> 1;

  const int L  = blockIdx.x;
  const int j  = L >> 3;
  const int qb = 31 - (j >> 2);
  const int bh = (L & 7) * 4 + (j & 3);
  const int b = bh >> 4, h = bh & 15;
  const int q0 = qb * 64;

  const size_t rowb = (size_t)b * 2048;
  const __bf16* Vb = Vt + (size_t)bh * 64 * 2048;

  const int srow = lane >> 3;
  const int scol = ((lane & 7) ^ srow) * 8;
  const int ck0 = wid * 2, ck1 = wid * 2 + 1;

  const int iql = qh * 32 + lq;

  bf16x8 qa[4];
#pragma unroll
  for (int ks = 0; ks < 4; ++ks)
    qa[ks] = *(const bf16x8*)
        &QA[(rowb + q0 + iql) * 1024 + h * 64 + ks * 16 + hl * 8];

  f32x16 oacc[2];
#pragma unroll
  for (int dt = 0; dt < 2; ++dt)
#pragma unroll
    for (int r = 0; r < 16; ++r) oacc[dt][r] = 0.f;
  float l_i = 0.f;

  const int kcmax = qb;

  GLDS16(Kp + (rowb + ck0 * 8 + srow) * 1024 + h * 64 + scol, &Ks[0][ck0 * 512]);
  GLDS16(Kp + (rowb + ck1 * 8 + srow) * 1024 + h * 64 + scol, &Ks[0][ck1 * 512]);
  GLDS16(Vb + (size_t)(ck0 * 8 + srow) * 2048 + scol, &Vs[0][ck0 * 512]);
  GLDS16(Vb + (size_t)(ck1 * 8 + srow) * 2048 + scol, &Vs[0][ck1 * 512]);
  __syncthreads();

  for (int kc = 0; kc <= kcmax; ++kc) {
    const int c = kc & 1;
    if (kc < kcmax) {
      const int t0 = (kc + 1) * 64;
      GLDS16(Kp + (rowb + t0 + ck0 * 8 + srow) * 1024 + h * 64 + scol,
             &Ks[c ^ 1][ck0 * 512]);
      GLDS16(Kp + (rowb + t0 + ck1 * 8 + srow) * 1024 + h * 64 + scol,
             &Ks[c ^ 1][ck1 * 512]);
      GLDS16(Vb + (size_t)(ck0 * 8 + srow) * 2048 + t0 + scol,
             &Vs[c ^ 1][ck0 * 512]);
      GLDS16(Vb + (size_t)(ck1 * 8 + srow) * 2048 + t0 + scol,
             &Vs[c ^ 1][ck1 * 512]);
    }

    const __bf16* Ksb = Ks[c];
    const __bf16* Vsb = Vs[c];

    f32x16 sacc;
#pragma unroll
    for (int r = 0; r < 16; ++r) sacc[r] = -16.f;
    __builtin_amdgcn_s_setprio(1);
#pragma unroll
    for (int ks = 0; ks < 4; ++ks) {
      bf16x8 kf = *(const bf16x8*)
          &Ksb[(kh * 32 + lq) * 64 + (((2 * ks + hl) ^ lq7) * 8)];
      sacc = __builtin_amdgcn_mfma_f32_32x32x16_bf16(kf, qa[ks], sacc, 0, 0, 0);
    }
    __builtin_amdgcn_s_setprio(0);

    const bool diag = (kc == kcmax);
    float p[16];
    float rsum = 0.f;
#pragma unroll
    for (int r = 0; r < 16; ++r) {
      float s = sacc[r];
      if (diag) {
        int kp = kh * 32 + (r & 3) + 8 * (r >> 2) + 4 * hl;
        if (kp > iql) s = -1e30f;
      }
      p[r] = __builtin_amdgcn_exp2f(s);
      rsum += p[r];
    }
    rsum += __shfl_xor(rsum, 32, 64);
    l_i += rsum;

    unsigned int cpk[8];
#pragma unroll
    for (int i = 0; i < 8; ++i)
      asm("v_cvt_pk_bf16_f32 %0, %1, %2"
          : "=v"(cpk[i]) : "v"(p[2 * i]), "v"(p[2 * i + 1]));
    bf16x8 pb[2];
#pragma unroll
    for (int k2 = 0; k2 < 2; ++k2) {
      unsigned int a0 = cpk[4 * k2 + 0], b0 = cpk[4 * k2 + 2];
      unsigned int a1 = cpk[4 * k2 + 1], b1 = cpk[4 * k2 + 3];
      asm("v_permlane32_swap_b32 %0, %1" : "+v"(a0), "+v"(b0));
      asm("v_permlane32_swap_b32 %0, %1" : "+v"(a1), "+v"(b1));
      union { unsigned int w[4]; bf16x8 v; } u;
      u.w[0] = a0; u.w[1] = a1; u.w[2] = b0; u.w[3] = b1;
      pb[k2] = u.v;
    }

    __builtin_amdgcn_s_setprio(1);
#pragma unroll
    for (int dt = 0; dt < 2; ++dt)
#pragma unroll
      for (int k2 = 0; k2 < 2; ++k2) {
        bf16x8 vf = *(const bf16x8*)
            &Vsb[(dt * 32 + lq) * 64 + (((4 * kh + 2 * k2 + hl) ^ lq7) * 8)];
        oacc[dt] = __builtin_amdgcn_mfma_f32_32x32x16_bf16(
            vf, pb[k2], oacc[dt], 0, 0, 0);
      }
    __builtin_amdgcn_s_setprio(0);

    __syncthreads();
  }

  float* Osf = (float*)&Ks[0][0];
  float* Lsf = (float*)&Vs[0][0];
  if (kh == 1) {
#pragma unroll
    for (int dt = 0; dt < 2; ++dt) {
      float* base = &Osf[((qh * 2 + dt) * 64 + lane) * 16];
#pragma unroll
      for (int g = 0; g < 4; ++g) {
        f32x4 w = {oacc[dt][4 * g], oacc[dt][4 * g + 1],
                   oacc[dt][4 * g + 2], oacc[dt][4 * g + 3]};
        *(f32x4*)&base[4 * g] = w;
      }
    }
    Lsf[qh * 64 + lane] = l_i;
  }
  __syncthreads();
  if (kh == 0) {
#pragma unroll
    for (int dt = 0; dt < 2; ++dt) {
      const float* base = &Osf[((qh * 2 + dt) * 64 + lane) * 16];
#pragma unroll
      for (int g = 0; g < 4; ++g) {
        f32x4 w = *(const f32x4*)&base[4 * g];
#pragma unroll
        for (int e = 0; e < 4; ++e) oacc[dt][4 * g + e] += w[e];
      }
    }
    float inv = 1.0f / (l_i + Lsf[qh * 64 + lane]);
#pragma unroll
    for (int dt = 0; dt < 2; ++dt)
#pragma unroll
      for (int g = 0; g < 4; ++g) {
        float a = oacc[dt][4 * g]     * inv, bb = oacc[dt][4 * g + 1] * inv;
        float cc = oacc[dt][4 * g + 2] * inv, dd = oacc[dt][4 * g + 3] * inv;
        unsigned int w0, w1;
        asm("v_cvt_pk_bf16_f32 %0, %1, %2" : "=v"(w0) : "v"(a), "v"(bb));
        asm("v_cvt_pk_bf16_f32 %0, %1, %2" : "=v"(w1) : "v"(cc), "v"(dd));
        u32x2 wv = {w0, w1};
        *(u32x2*)&QA[(rowb + q0 + iql) * 1024 + h * 64 + dt * 32 + 8 * g + 4 * hl] = wv;
      }
  }
}

// ---------------------------------------------------------------------------
// Output GEMM: out[m][n] = sum_k AO[m][k]*Wo[n][k], fp32 out. 64x128 tiles
// (512 blocks, 2 blocks/CU), BK=32 + swizzle, overlay epilogue.
// ---------------------------------------------------------------------------
__global__ __launch_bounds__(256) void gemm_out(
    const __bf16* __restrict__ AO, const __bf16* __restrict__ Wob,
    float* __restrict__ Of)
{
  __shared__ __bf16 Smem[8704];   // As 64x32 | Bs 128x32 ; EsF overlays (17KB)
  __bf16* As = Smem;
  __bf16* Bs = Smem + 64 * 32;

  const int tid  = threadIdx.x;
  const int lane = tid & 63;
  const int wid  = tid >> 6;
  const int quad = lane >> 4;
  const int l16  = lane & 15;
  const int wm   = (wid >> 1) * 32;     // 2 m-halves of 32 rows
  const int wn   = (wid & 1) * 64;      // 2 n-halves of 64 cols

  const int lin = blockIdx.x;           // 512 blocks
  const int n0  = (lin & 7) * 128;      // n-column tied to XCD
  const int m0  = (lin >> 3) * 64;      // 64 m-tiles

  const int r0 = tid >> 2, c0 = tid & 3;     // staging row 0..63, chunk 0..3
  const int scx = (c0 ^ ((r0 >> 1) & 3)) * 8;
  const int fq  = (l16 >> 1) & 3;

  f32x4 acc[2][4];
  for (int i = 0; i < 2; ++i)
    for (int j = 0; j < 4; ++j) acc[i][j] = zero4();

  for (int k0 = 0; k0 < 1024; k0 += 32) {
    __syncthreads();
    GLDS16(AO  + (size_t)(m0 + r0) * 1024 + k0 + scx, &As[(size_t)tid * 8]);
    GLDS16(Wob + (size_t)(n0 + r0) * 1024 + k0 + scx, &Bs[(size_t)tid * 8]);
    GLDS16(Wob + (size_t)(n0 + 64 + r0) * 1024 + k0 + scx,
           &Bs[(size_t)(tid + 256) * 8]);
    __syncthreads();

    bf16x8 af[2], bfr[4];
#pragma unroll
    for (int i = 0; i < 2; ++i)
      af[i] = *(const bf16x8*)
          &As[(wm + i * 16 + l16) * 32 + ((quad ^ fq) * 8)];
#pragma unroll
    for (int i = 0; i < 4; ++i)
      bfr[i] = *(const bf16x8*)
          &Bs[(wn + i * 16 + l16) * 32 + ((quad ^ fq) * 8)];
#pragma unroll
    for (int mt = 0; mt < 2; ++mt)
#pragma unroll
      for (int nt = 0; nt < 4; ++nt)
        acc[mt][nt] = __builtin_amdgcn_mfma_f32_16x16x32_bf16(
            af[mt], bfr[nt], acc[mt][nt], 0, 0, 0);
  }

  __syncthreads();   // As/Bs dead; overlay f32 transpose tiles

  float* es = (float*)&Smem[0] + wid * 1088;   // 16 x 68 f32, per-wave
  const int rl = lane >> 4, ch = lane & 15;
  for (int mt = 0; mt < 2; ++mt) {
    for (int nt = 0; nt < 4; ++nt)
      for (int r = 0; r < 4; ++r)
        es[(4 * quad + r) * 68 + nt * 16 + l16] = acc[mt][nt][r];
    size_t g0 = (size_t)(m0 + wm + mt * 16 + rl) * 1024 + n0 + wn + ch * 4;
    *(f32x4*)&Of[g0]             = *(const f32x4*)&es[rl * 68 + ch * 4];
    *(f32x4*)&Of[g0 + 4 * 1024]  = *(const f32x4*)&es[(rl + 4) * 68 + ch * 4];
    *(f32x4*)&Of[g0 + 8 * 1024]  = *(const f32x4*)&es[(rl + 8) * 68 + ch * 4];
    *(f32x4*)&Of[g0 + 12 * 1024] = *(const f32x4*)&es[(rl + 12) * 68 + ch * 4];
    __syncthreads();   // es reuse between mt iterations (per-wave slice; keeps
                       // waves' stores ordered before next fill)
  }
}

// copy 8 bf16/lane
__global__ __launch_bounds__(256) void copy_bf16x8(
    const __bf16* __restrict__ src, __bf16* __restrict__ dst)
{
  size_t i = ((size_t)blockIdx.x * 256 + threadIdx.x) * 8;
  *(bf16x8*)&dst[i] = *(const bf16x8*)&src[i];
}

// ---------------------------------------------------------------------------
extern "C" void kernel_launch(void* const* d_in, const int* in_sizes, int n_in,
                              void* d_out, int out_size, void* d_ws, size_t ws_size,
                              hipStream_t stream) {
  const float* x  = (const float*)d_in[0];
  const float* Wq = (const float*)d_in[1];
  const float* Wk = (const float*)d_in[2];
  const float* Wv = (const float*)d_in[3];
  const float* Wo = (const float*)d_in[4];
  float* out = (float*)d_out;

  const size_t NELT = (size_t)4194304;             // 4M elems (8 MiB bf16)
  __bf16* Qp = (__bf16*)d_ws;        // plain Q, becomes AO in-place
  __bf16* Kp = Qp + NELT;            // plain K, later holds Wo bf16
  __bf16* Vt = Kp + NELT;            // V^T [bh][d][t]
  __bf16* xb = (__bf16*)d_out;       // d_out[0:8MB) scratch: x bf16
  __bf16* Wb = xb + NELT;            // d_out[8:16MB): W* bf16

  prep<<<dim3(4096), 256, 0, stream>>>(x, Wq, Wk, Wv, Wo, xb, Wb);
  gemm_qkv<<<dim3(768), 256, 0, stream>>>(xb, Wb, Qp, Kp, Vt);
  attn_fwd<<<dim3(1024), 256, 0, stream>>>(Qp, Kp, Vt);
  copy_bf16x8<<<dim3(512), 256, 0, stream>>>(Wb + 3 * NELT / 4, Kp);
  gemm_out<<<dim3(512), 256, 0, stream>>>(Qp, Kp, out);
}